// Round 1
// baseline (216.467 us; speedup 1.0000x reference)
//
#include <hip/hip_runtime.h>
#include <hip/hip_bf16.h>

// TDCPQueryAttentionPool fused kernel for MI355X (gfx950).
// B=8, N=4096, M=4, E=512, H=8, d=64. tokens = 32768.
//
// Factorization: scores[t,h,m] = wsc[h]·x[t,m] + scoreb[h], wsc[h] = Wk_h^T qh_h
// (K-projection GEMM eliminated). Then V-GEMM [128 rows x 512]x[512x512] per
// 32-token tile fused with score-MFMA, lane-local softmax + blend, out-proj
// GEMM, LayerNorm. One HBM pass over x.

typedef float  f32x4  __attribute__((ext_vector_type(4)));
typedef float  f32x16 __attribute__((ext_vector_type(16)));
typedef short  short8 __attribute__((ext_vector_type(8)));

__device__ __forceinline__ unsigned short f2bf(float f) {
  unsigned int x = __float_as_uint(f);
  unsigned int r = (x + 0x7fffu + ((x >> 16) & 1u)) >> 16;  // RNE
  return (unsigned short)r;
}

__device__ __forceinline__ short8 pack8(const f32x4& a, const f32x4& b) {
  short8 r;
  r[0] = (short)f2bf(a[0]); r[1] = (short)f2bf(a[1]);
  r[2] = (short)f2bf(a[2]); r[3] = (short)f2bf(a[3]);
  r[4] = (short)f2bf(b[0]); r[5] = (short)f2bf(b[1]);
  r[6] = (short)f2bf(b[2]); r[7] = (short)f2bf(b[3]);
  return r;
}

__device__ __forceinline__ void mfma32(f32x16& c, short8 a, short8 b) {
  asm("v_mfma_f32_32x32x16_bf16 %0, %1, %2, %0" : "+v"(c) : "v"(a), "v"(b));
}
__device__ __forceinline__ void mfma16(f32x4& c, short8 a, short8 b) {
  asm("v_mfma_f32_16x16x32_bf16 %0, %1, %2, %0" : "+v"(c) : "v"(a), "v"(b));
}

// ---------------------------------------------------------------------------
// K0: precompute (per call, d_ws is poisoned before timing):
//  blocks 0..7   : qh slice (64 vals), wsc[h][512] -> wscB frags, scoreb[h]
//  blocks 8..135 : Wv / Wo -> fragment-linear bf16 (B-operand layout,
//                  slot convention: lane ln holds col=ln&31, k=(ln>>5)*8+j)
// ---------------------------------------------------------------------------
__global__ void __launch_bounds__(512) tdcp_k0(
    const float* __restrict__ q_param, const float* __restrict__ in_w,
    const float* __restrict__ in_b, const float* __restrict__ out_w,
    float* __restrict__ scoreb, unsigned short* __restrict__ wscB,
    unsigned short* __restrict__ WvB, unsigned short* __restrict__ WoB)
{
  const int tid = threadIdx.x;
  const int blk = blockIdx.x;
  if (blk < 8) {
    const int h = blk;
    __shared__ float qls[512];
    __shared__ float qs[64];
    qls[tid] = q_param[tid];
    __syncthreads();
    {  // qh[h*64+io] = (Wq[h*64+io]·q + bq)*0.125 ; 8 threads per output
      const int io = tid >> 3, sub = tid & 7;
      const float* wrow = in_w + (size_t)(h * 64 + io) * 512;
      float v = 0.f;
      #pragma unroll 8
      for (int ee = 0; ee < 64; ++ee) {
        const int e = sub + (ee << 3);
        v += wrow[e] * qls[e];
      }
      v += __shfl_xor(v, 1); v += __shfl_xor(v, 2); v += __shfl_xor(v, 4);
      if (sub == 0) qs[io] = (v + in_b[h * 64 + io]) * 0.125f;
    }
    __syncthreads();
    {  // wsc[h][e] = sum_j qs[j] * Wk[h*64+j][e]; write into 16x16x32 B-frag
      const int e = tid;
      const float* wk = in_w + (size_t)(512 + h * 64) * 512 + e;
      float v = 0.f;
      #pragma unroll 8
      for (int jj = 0; jj < 64; ++jj) v += qs[jj] * wk[jj * 512];
      const int s32 = e >> 5, g = (e & 31) >> 3, j = e & 7;
      wscB[((s32 << 6) + h + (g << 4)) * 8 + j] = f2bf(v);
      wscB[((s32 << 6) + (h + 8) + (g << 4)) * 8 + j] = 0;  // pad heads 8..15
    }
    if (tid < 64) {  // scoreb[h] = qs · bk_h
      float v = qs[tid] * in_b[512 + h * 64 + tid];
      v += __shfl_xor(v, 1);  v += __shfl_xor(v, 2);  v += __shfl_xor(v, 4);
      v += __shfl_xor(v, 8);  v += __shfl_xor(v, 16); v += __shfl_xor(v, 32);
      if (tid == 0) scoreb[h] = v;
    }
    if (blk == 0 && tid >= 64 && tid < 72) scoreb[tid - 56] = 0.f;
  } else {
    // Wv / Wo fragment conversion. B[k=e][col=f] = W[f][e].
    const int mb = blk - 8;
    const bool isWo = mb >= 64;
    const float* src = isWo ? out_w : (in_w + (size_t)1024 * 512);
    unsigned short* dst = isWo ? WoB : WvB;
    const int slot = ((mb & 63) << 9) + tid;        // 0..32767
    const int ct = slot >> 11, kt = (slot >> 6) & 31, ln = slot & 63;
    const float* p = src + (size_t)(ct * 32 + (ln & 31)) * 512
                         + kt * 16 + ((ln >> 5) << 3);
    const f32x4 u0 = *(const f32x4*)(p);
    const f32x4 u1 = *(const f32x4*)(p + 4);
    *(short8*)(dst + slot * 8) = pack8(u0, u1);
  }
}

// ---------------------------------------------------------------------------
// K1: fused attention-pool. 1024 blocks x 512 threads, 32 tokens/block.
// LDS 64 KB: [0..32K) x-slice double buffer (later a_lds + LN stats),
//            [32K..64K) o_mid fragment buffer.
// ---------------------------------------------------------------------------
__global__ void __launch_bounds__(512, 2) tdcp_k1(
    const float* __restrict__ f0, const float* __restrict__ f1,
    const float* __restrict__ f2, const float* __restrict__ f3,
    const float* __restrict__ in_b,
    const float* __restrict__ scoreb, const unsigned short* __restrict__ wscB,
    const unsigned short* __restrict__ WvB, const unsigned short* __restrict__ WoB,
    const float* __restrict__ out_b, const float* __restrict__ gamma,
    const float* __restrict__ beta, float* __restrict__ out)
{
  __shared__ __align__(16) char smem[65536];
  const int tid = threadIdx.x;
  const int w = tid >> 6;         // wave 0..7, owns cols [64w, 64w+64) = head w
  const int l = tid & 63;
  const int tok0 = blockIdx.x << 5;

  // ---- staging map: row r = t*4+m (0..127), 64-elem step chunks ----
  const int sr = tid >> 2;                  // row
  const int se = (tid & 3) << 4;            // e offset in 64-chunk (0,16,32,48)
  const int sm = sr & 3;
  const int stk = sr >> 2;
  const float* fsrc = (sm == 0 ? f0 : sm == 1 ? f1 : sm == 2 ? f2 : f3)
                      + (size_t)(tok0 + stk) * 512 + se;
  const int swo = (se << 8) + ((sr >> 5) << 10) + ((sr & 31) << 4);

  f32x16 acc[4][2];                         // V accum: [rowtile][ct]
  f32x4 sacc;                               // score accum (16x16)
  #pragma unroll
  for (int i = 0; i < 4; ++i)
    #pragma unroll
    for (int c = 0; c < 2; ++c)
      #pragma unroll
      for (int r = 0; r < 16; ++r) acc[i][c][r] = 0.f;
  sacc[0] = sacc[1] = sacc[2] = sacc[3] = 0.f;

  const int ct0 = w << 1;
  const int a_off = l << 4;
  const int s_off = ((w >> 1) << 10)
      + ((((w & 1) << 4) | (l & 15) | (((l >> 4) & 1) << 5)) << 4);
  const int s_kadd = (l >> 5) << 12;

  // ---- prologue: stage step 0 ----
  {
    const f32x4 a0 = *(const f32x4*)(fsrc);
    const f32x4 a1 = *(const f32x4*)(fsrc + 4);
    const f32x4 a2 = *(const f32x4*)(fsrc + 8);
    const f32x4 a3 = *(const f32x4*)(fsrc + 12);
    *(short8*)(smem + swo) = pack8(a0, a1);
    *(short8*)(smem + swo + 512) = pack8(a2, a3);
  }
  __syncthreads();

  // ---- main streamed pass: V-GEMM + score-MFMA ----
  #pragma unroll 1
  for (int step = 0; step < 8; ++step) {
    char* cur = smem + ((step & 1) << 14);
    f32x4 ld0, ld1, ld2, ld3;
    const bool more = (step + 1) < 8;
    if (more) {
      const float* p = fsrc + ((step + 1) << 6);
      ld0 = *(const f32x4*)(p);
      ld1 = *(const f32x4*)(p + 4);
      ld2 = *(const f32x4*)(p + 8);
      ld3 = *(const f32x4*)(p + 12);
    }
    #pragma unroll
    for (int kt4 = 0; kt4 < 4; ++kt4) {
      const int kt = (step << 2) + kt4;
      const short8 b0 = *(const short8*)(WvB + (((ct0 * 32 + kt) << 6) + l) * 8);
      const short8 b1 = *(const short8*)(WvB + ((((ct0 + 1) * 32 + kt) << 6) + l) * 8);
      #pragma unroll
      for (int rt = 0; rt < 4; ++rt) {
        const short8 a = *(const short8*)(cur + (kt4 << 12) + (rt << 10) + a_off);
        mfma32(acc[rt][0], a, b0);
        mfma32(acc[rt][1], a, b1);
      }
      if ((kt4 & 1) == 0) {
        const int s32 = (step << 1) + (kt4 >> 1);
        const short8 sa = *(const short8*)(cur + (kt4 << 12) + s_kadd + s_off);
        const short8 sb = *(const short8*)(wscB + ((s32 << 6) + l) * 8);
        mfma16(sacc, sa, sb);
      }
    }
    if (more) {
      char* nxt = smem + (((step + 1) & 1) << 14);
      *(short8*)(nxt + swo) = pack8(ld0, ld1);
      *(short8*)(nxt + swo + 512) = pack8(ld2, ld3);
    }
    __syncthreads();
  }

  // ---- softmax over m (lane-local: reg = m), write a[t][h][4] to LDS ----
  {
    const int hh = l & 15;
    if (hh < 8) {
      const float sb = scoreb[hh];
      const float s0 = sacc[0] + sb, s1 = sacc[1] + sb;
      const float s2 = sacc[2] + sb, s3 = sacc[3] + sb;
      const float mx = fmaxf(fmaxf(s0, s1), fmaxf(s2, s3));
      const float e0 = __expf(s0 - mx), e1 = __expf(s1 - mx);
      const float e2 = __expf(s2 - mx), e3 = __expf(s3 - mx);
      const float inv = 1.f / (e0 + e1 + e2 + e3);
      f32x4 av; av[0] = e0 * inv; av[1] = e1 * inv; av[2] = e2 * inv; av[3] = e3 * inv;
      const int t = (w << 2) + (l >> 4);
      *(f32x4*)(smem + (((t << 3) + hh) << 4)) = av;
    }
  }
  __syncthreads();

  // ---- blend: o_mid[t][f] = sum_m a[t][h][m]*V + bv[f]; scatter to frag LDS ----
  {
    unsigned short* omid = (unsigned short*)(smem + 32768);
    #pragma unroll
    for (int c2 = 0; c2 < 2; ++c2) {
      const int ff = ((ct0 + c2) << 5) + (l & 31);
      const float bvf = in_b[1024 + ff];
      const int ktf = ff >> 4;
      const int laneL = ((l >> 3) & 1) << 5;
      const int elem = ff & 7;
      #pragma unroll
      for (int rt = 0; rt < 4; ++rt) {
        #pragma unroll
        for (int tt = 0; tt < 4; ++tt) {
          const int t = (rt << 3) + (tt << 1) + (l >> 5);
          const f32x4 av = *(const f32x4*)(smem + (((t << 3) + w) << 4));
          const float o = av[0] * acc[rt][c2][tt * 4 + 0]
                        + av[1] * acc[rt][c2][tt * 4 + 1]
                        + av[2] * acc[rt][c2][tt * 4 + 2]
                        + av[3] * acc[rt][c2][tt * 4 + 3] + bvf;
          omid[((ktf << 6) + t + laneL) * 8 + elem] = f2bf(o);
        }
      }
    }
  }
  __syncthreads();

  // ---- out-projection GEMM: [32 x 512] x Wo^T ----
  f32x16 oa0, oa1;
  #pragma unroll
  for (int r = 0; r < 16; ++r) { oa0[r] = 0.f; oa1[r] = 0.f; }
  #pragma unroll 4
  for (int kt = 0; kt < 32; ++kt) {
    const short8 a = *(const short8*)(smem + 32768 + (kt << 10) + a_off);
    const short8 b0 = *(const short8*)(WoB + (((ct0 * 32 + kt) << 6) + l) * 8);
    const short8 b1 = *(const short8*)(WoB + ((((ct0 + 1) * 32 + kt) << 6) + l) * 8);
    mfma32(oa0, a, b0);
    mfma32(oa1, a, b1);
  }
  asm volatile("s_nop 7\n\ts_nop 7\n\ts_nop 7" ::);  // MFMA->VALU hazard pad

  // ---- LayerNorm: per-wave partial stats -> LDS -> combine -> store ----
  {
    const int g0 = (ct0 << 5) + (l & 31);
    const int g1 = g0 + 32;
    const float ob0 = out_b[g0], ob1 = out_b[g1];
    const float gm0 = gamma[g0], gm1 = gamma[g1];
    const float bt0 = beta[g0],  bt1 = beta[g1];
    float* stats = (float*)(smem + 4096);  // [32][8 waves][2]
    #pragma unroll
    for (int r = 0; r < 16; ++r) {
      const float v0 = oa0[r] + ob0, v1 = oa1[r] + ob1;
      float s = v0 + v1, qq = v0 * v0 + v1 * v1;
      s += __shfl_xor(s, 16); qq += __shfl_xor(qq, 16);
      s += __shfl_xor(s, 8);  qq += __shfl_xor(qq, 8);
      s += __shfl_xor(s, 4);  qq += __shfl_xor(qq, 4);
      s += __shfl_xor(s, 2);  qq += __shfl_xor(qq, 2);
      s += __shfl_xor(s, 1);  qq += __shfl_xor(qq, 1);
      if ((l & 31) == 0) {
        const int t = (r & 3) + ((r >> 2) << 3) + ((l >> 5) << 2);
        stats[(t << 4) + (w << 1)] = s;
        stats[(t << 4) + (w << 1) + 1] = qq;
      }
    }
    __syncthreads();
    #pragma unroll
    for (int r = 0; r < 16; ++r) {
      const int t = (r & 3) + ((r >> 2) << 3) + ((l >> 5) << 2);
      const float* st = stats + (t << 4);
      float s = 0.f, qq = 0.f;
      #pragma unroll
      for (int ww = 0; ww < 8; ++ww) { s += st[2 * ww]; qq += st[2 * ww + 1]; }
      const float mu = s * 0.001953125f;
      const float rs = rsqrtf(qq * 0.001953125f - mu * mu + 1e-5f);
      const float v0 = oa0[r] + ob0, v1 = oa1[r] + ob1;
      float* op = out + (size_t)(tok0 + t) * 512;
      op[g0] = (v0 - mu) * rs * gm0 + bt0;
      op[g1] = (v1 - mu) * rs * gm1 + bt1;
    }
  }
}

extern "C" void kernel_launch(void* const* d_in, const int* in_sizes, int n_in,
                              void* d_out, int out_size, void* d_ws, size_t ws_size,
                              hipStream_t stream) {
  const float* f0      = (const float*)d_in[0];
  const float* f1      = (const float*)d_in[1];
  const float* f2      = (const float*)d_in[2];
  const float* f3      = (const float*)d_in[3];
  const float* q_param = (const float*)d_in[4];
  const float* in_w    = (const float*)d_in[5];
  const float* in_b    = (const float*)d_in[6];
  const float* out_w   = (const float*)d_in[7];
  const float* out_b   = (const float*)d_in[8];
  const float* gamma   = (const float*)d_in[9];
  const float* beta    = (const float*)d_in[10];
  float* out = (float*)d_out;

  char* ws = (char*)d_ws;
  float* scoreb          = (float*)ws;                      // 64 B (16 f32)
  unsigned short* wscB   = (unsigned short*)(ws + 4096);    // 16 KB
  unsigned short* WvB    = (unsigned short*)(ws + 20480);   // 512 KB
  unsigned short* WoB    = (unsigned short*)(ws + 544768);  // 512 KB

  tdcp_k0<<<136, 512, 0, stream>>>(q_param, in_w, in_b, out_w,
                                   scoreb, wscB, WvB, WoB);
  tdcp_k1<<<1024, 512, 0, stream>>>(f0, f1, f2, f3, in_b,
                                    scoreb, wscB, WvB, WoB,
                                    out_b, gamma, beta, out);
}

// Round 2
// 152.591 us; speedup vs baseline: 1.4186x; 1.4186x over previous
//
#include <hip/hip_runtime.h>
#include <hip/hip_bf16.h>

// TDCPQueryAttentionPool fused kernel for MI355X (gfx950).
// B=8, N=4096, M=4, E=512, H=8, d=64. tokens = 32768.
//
// R2: counted-vmcnt pipeline. All main-loop global loads are inline-asm
// global_load_dwordx4 with manual s_waitcnt vmcnt(N) (never 0 mid-loop),
// raw s_barrier (no vmcnt drain), 3 rotating LDS x-buffers, x issued 3
// steps ahead, Wv B-frags 1 step ahead, wsc in LDS, XOR-swizzled staging.

typedef float  f32x4  __attribute__((ext_vector_type(4)));
typedef float  f32x16 __attribute__((ext_vector_type(16)));
typedef short  short8 __attribute__((ext_vector_type(8)));

__device__ __forceinline__ unsigned short f2bf(float f) {
  unsigned int x = __float_as_uint(f);
  unsigned int r = (x + 0x7fffu + ((x >> 16) & 1u)) >> 16;  // RNE
  return (unsigned short)r;
}

__device__ __forceinline__ short8 pack8(const f32x4& a, const f32x4& b) {
  short8 r;
  r[0] = (short)f2bf(a[0]); r[1] = (short)f2bf(a[1]);
  r[2] = (short)f2bf(a[2]); r[3] = (short)f2bf(a[3]);
  r[4] = (short)f2bf(b[0]); r[5] = (short)f2bf(b[1]);
  r[6] = (short)f2bf(b[2]); r[7] = (short)f2bf(b[3]);
  return r;
}

__device__ __forceinline__ void mfma32(f32x16& c, short8 a, short8 b) {
  asm("v_mfma_f32_32x32x16_bf16 %0, %1, %2, %0" : "+v"(c) : "v"(a), "v"(b));
}
__device__ __forceinline__ void mfma16(f32x4& c, short8 a, short8 b) {
  asm("v_mfma_f32_16x16x32_bf16 %0, %1, %2, %0" : "+v"(c) : "v"(a), "v"(b));
}

__device__ __forceinline__ void gld4f(f32x4& d, const float* p) {
  asm volatile("global_load_dwordx4 %0, %1, off" : "=v"(d) : "v"(p));
}
__device__ __forceinline__ void gld4s(short8& d, const unsigned short* p) {
  asm volatile("global_load_dwordx4 %0, %1, off" : "=v"(d) : "v"(p));
}

__device__ __forceinline__ void wxv4(f32x4& a, f32x4& b, f32x4& c, f32x4& d) {
  asm volatile("s_waitcnt vmcnt(4)" : "+v"(a), "+v"(b), "+v"(c), "+v"(d));
}
__device__ __forceinline__ void wxv8(f32x4& a, f32x4& b, f32x4& c, f32x4& d) {
  asm volatile("s_waitcnt vmcnt(8)" : "+v"(a), "+v"(b), "+v"(c), "+v"(d));
}
__device__ __forceinline__ void wxv12(f32x4& a, f32x4& b, f32x4& c, f32x4& d) {
  asm volatile("s_waitcnt vmcnt(12)" : "+v"(a), "+v"(b), "+v"(c), "+v"(d));
}
__device__ __forceinline__ void wbv4(short8& a, short8& b, short8& c, short8& d,
                                     short8& e, short8& f, short8& g, short8& h) {
  asm volatile("s_waitcnt vmcnt(4)"
               : "+v"(a), "+v"(b), "+v"(c), "+v"(d),
                 "+v"(e), "+v"(f), "+v"(g), "+v"(h));
}
__device__ __forceinline__ void wbv0(short8& a, short8& b, short8& c, short8& d,
                                     short8& e, short8& f, short8& g, short8& h) {
  asm volatile("s_waitcnt vmcnt(0)"
               : "+v"(a), "+v"(b), "+v"(c), "+v"(d),
                 "+v"(e), "+v"(f), "+v"(g), "+v"(h));
}

// ---------------------------------------------------------------------------
// K0: precompute (unchanged from R1; correctness-verified).
// ---------------------------------------------------------------------------
__global__ void __launch_bounds__(512) tdcp_k0(
    const float* __restrict__ q_param, const float* __restrict__ in_w,
    const float* __restrict__ in_b, const float* __restrict__ out_w,
    float* __restrict__ scoreb, unsigned short* __restrict__ wscB,
    unsigned short* __restrict__ WvB, unsigned short* __restrict__ WoB)
{
  const int tid = threadIdx.x;
  const int blk = blockIdx.x;
  if (blk < 8) {
    const int h = blk;
    __shared__ float qls[512];
    __shared__ float qs[64];
    qls[tid] = q_param[tid];
    __syncthreads();
    {
      const int io = tid >> 3, sub = tid & 7;
      const float* wrow = in_w + (size_t)(h * 64 + io) * 512;
      float v = 0.f;
      #pragma unroll 8
      for (int ee = 0; ee < 64; ++ee) {
        const int e = sub + (ee << 3);
        v += wrow[e] * qls[e];
      }
      v += __shfl_xor(v, 1); v += __shfl_xor(v, 2); v += __shfl_xor(v, 4);
      if (sub == 0) qs[io] = (v + in_b[h * 64 + io]) * 0.125f;
    }
    __syncthreads();
    {
      const int e = tid;
      const float* wk = in_w + (size_t)(512 + h * 64) * 512 + e;
      float v = 0.f;
      #pragma unroll 8
      for (int jj = 0; jj < 64; ++jj) v += qs[jj] * wk[jj * 512];
      const int s32 = e >> 5, g = (e & 31) >> 3, j = e & 7;
      wscB[((s32 << 6) + h + (g << 4)) * 8 + j] = f2bf(v);
      wscB[((s32 << 6) + (h + 8) + (g << 4)) * 8 + j] = 0;
    }
    if (tid < 64) {
      float v = qs[tid] * in_b[512 + h * 64 + tid];
      v += __shfl_xor(v, 1);  v += __shfl_xor(v, 2);  v += __shfl_xor(v, 4);
      v += __shfl_xor(v, 8);  v += __shfl_xor(v, 16); v += __shfl_xor(v, 32);
      if (tid == 0) scoreb[h] = v;
    }
    if (blk == 0 && tid >= 64 && tid < 72) scoreb[tid - 56] = 0.f;
  } else {
    const int mb = blk - 8;
    const bool isWo = mb >= 64;
    const float* src = isWo ? out_w : (in_w + (size_t)1024 * 512);
    unsigned short* dst = isWo ? WoB : WvB;
    const int slot = ((mb & 63) << 9) + tid;
    const int ct = slot >> 11, kt = (slot >> 6) & 31, ln = slot & 63;
    const float* p = src + (size_t)(ct * 32 + (ln & 31)) * 512
                         + kt * 16 + ((ln >> 5) << 3);
    const f32x4 u0 = *(const f32x4*)(p);
    const f32x4 u1 = *(const f32x4*)(p + 4);
    *(short8*)(dst + slot * 8) = pack8(u0, u1);
  }
}

// ---------------------------------------------------------------------------
// K1: fused attention-pool, counted-vmcnt pipeline.
// LDS map: [0,48K) three 16K x-buffers; [48K,64K) wsc frags.
// After main loop: omid [0,32K), av [32K,36K), stats [36K,38K).
// ---------------------------------------------------------------------------
__global__ void __launch_bounds__(512, 2) tdcp_k1(
    const float* __restrict__ f0, const float* __restrict__ f1,
    const float* __restrict__ f2, const float* __restrict__ f3,
    const float* __restrict__ in_b,
    const float* __restrict__ scoreb, const unsigned short* __restrict__ wscB,
    const unsigned short* __restrict__ WvB, const unsigned short* __restrict__ WoB,
    const float* __restrict__ out_b, const float* __restrict__ gamma,
    const float* __restrict__ beta, float* __restrict__ out)
{
  __shared__ __align__(16) char smem[65536];
  const int tid = threadIdx.x;
  const int w = tid >> 6;         // wave 0..7: owns output cols [64w,64w+64)
  const int l = tid & 63;
  const int tok0 = blockIdx.x << 5;

  // ---- wsc -> LDS (16 KB), before the pipeline starts ----
  {
    const f32x4* wsrc = (const f32x4*)wscB;
    f32x4* wdst = (f32x4*)(smem + 49152);
    wdst[tid * 2] = wsrc[tid * 2];
    wdst[tid * 2 + 1] = wsrc[tid * 2 + 1];
  }

  // ---- staging map: row sr = t*4+m (0..127), chunk = 16-float sub ----
  const int sr = tid >> 2;
  const int chunk = tid & 3;
  const int sm = sr & 3;
  const int stk = sr >> 2;
  const float* fsrc = (sm == 0 ? f0 : sm == 1 ? f1 : sm == 2 ? f2 : f3)
                      + (size_t)(tok0 + stk) * 512 + (chunk << 4);
  const int wbase = (chunk << 12) + ((sr >> 5) << 10)
                  + (((sr & 31) << 4) ^ (chunk << 5));

  // ---- fragment-read bases ----
  const int aO = ((l >> 5) << 9) + ((l & 31) << 4);
  const int sBase = ((w >> 1) << 10) + (((l >> 4) & 1) << 9)
                  + ((((w & 1) << 4) | (l & 15)) << 4);
  const int ct0 = w << 1;
  const unsigned short* wv0 = WvB + (((ct0 * 32) << 6) + l) * 8;
  const unsigned short* wv1 = WvB + ((((ct0 + 1) * 32) << 6) + l) * 8;
  const unsigned short* wscL = (const unsigned short*)(smem + 49152);

  f32x16 acc[4][2];
  f32x4 sacc;
  #pragma unroll
  for (int i = 0; i < 4; ++i)
    #pragma unroll
    for (int c = 0; c < 2; ++c)
      #pragma unroll
      for (int r = 0; r < 16; ++r) acc[i][c][r] = 0.f;
  sacc[0] = sacc[1] = sacc[2] = sacc[3] = 0.f;

  f32x4 lx[2][4];
  short8 bb[2][8];

  // ---- prologue: L0,L1 issue; pack buf0; B0 issue; L2 issue; barrier ----
  gld4f(lx[0][0], fsrc);      gld4f(lx[0][1], fsrc + 4);
  gld4f(lx[0][2], fsrc + 8);  gld4f(lx[0][3], fsrc + 12);
  gld4f(lx[1][0], fsrc + 64); gld4f(lx[1][1], fsrc + 68);
  gld4f(lx[1][2], fsrc + 72); gld4f(lx[1][3], fsrc + 76);
  wxv4(lx[0][0], lx[0][1], lx[0][2], lx[0][3]);
  *(short8*)(smem + wbase) = pack8(lx[0][0], lx[0][1]);
  *(short8*)(smem + wbase + 512) = pack8(lx[0][2], lx[0][3]);
  #pragma unroll
  for (int j = 0; j < 4; ++j) {
    gld4s(bb[0][2 * j],     wv0 + j * 512);
    gld4s(bb[0][2 * j + 1], wv1 + j * 512);
  }
  gld4f(lx[0][0], fsrc + 128); gld4f(lx[0][1], fsrc + 132);
  gld4f(lx[0][2], fsrc + 136); gld4f(lx[0][3], fsrc + 140);
  asm volatile("s_waitcnt lgkmcnt(0)" ::: "memory");
  __builtin_amdgcn_s_barrier();
  asm volatile("" ::: "memory");

  // ---- main loop: 8 steps of 64 e-elements ----
  #pragma unroll
  for (int s = 0; s < 8; ++s) {
    // pack buf[(s+1)%3] from lx[(s+1)&1] (holds L(s+1))
    if (s < 7) {
      f32x4 (&L)[4] = lx[(s + 1) & 1];
      if (s < 6) wxv12(L[0], L[1], L[2], L[3]);
      else       wxv8(L[0], L[1], L[2], L[3]);
      char* nb = smem + 16384 * ((s + 1) % 3);
      *(short8*)(nb + wbase) = pack8(L[0], L[1]);
      *(short8*)(nb + wbase + 512) = pack8(L[2], L[3]);
    }
    asm volatile("s_waitcnt lgkmcnt(0)" ::: "memory");
    __builtin_amdgcn_s_barrier();
    asm volatile("" ::: "memory");

    // compute step s from buf[s%3]
    short8 (&b)[8] = bb[s & 1];
    if (s < 6) wbv4(b[0], b[1], b[2], b[3], b[4], b[5], b[6], b[7]);
    else       wbv0(b[0], b[1], b[2], b[3], b[4], b[5], b[6], b[7]);
    char* cur = smem + 16384 * (s % 3);
    const short8 sb0 = *(const short8*)(wscL + (((2 * s) << 6) + l) * 8);
    const short8 sb1 = *(const short8*)(wscL + (((2 * s + 1) << 6) + l) * 8);
    #pragma unroll
    for (int kt4 = 0; kt4 < 4; ++kt4) {
      #pragma unroll
      for (int rt = 0; rt < 4; ++rt) {
        const short8 a = *(const short8*)(cur + (kt4 << 12) + (rt << 10)
                                          + (aO ^ (kt4 << 5)));
        mfma32(acc[rt][0], a, b[kt4 * 2]);
        mfma32(acc[rt][1], a, b[kt4 * 2 + 1]);
      }
      if ((kt4 & 1) == 0) {
        const int schunk = kt4 + (l >> 5);
        const short8 sa = *(const short8*)(cur + (schunk << 12)
                                           + (sBase ^ ((schunk & 3) << 5)));
        mfma16(sacc, sa, (kt4 == 0) ? sb0 : sb1);
      }
    }
    // issue B(s+1) (1 step ahead) and L(s+3) (3 steps ahead)
    if (s < 7) {
      short8 (&nbf)[8] = bb[(s + 1) & 1];
      #pragma unroll
      for (int j = 0; j < 4; ++j) {
        gld4s(nbf[2 * j],     wv0 + ((s + 1) * 4 + j) * 512);
        gld4s(nbf[2 * j + 1], wv1 + ((s + 1) * 4 + j) * 512);
      }
    }
    if (s < 5) {
      f32x4 (&L)[4] = lx[(s + 3) & 1];
      const float* p = fsrc + ((s + 3) << 6);
      gld4f(L[0], p); gld4f(L[1], p + 4); gld4f(L[2], p + 8); gld4f(L[3], p + 12);
    }
  }
  asm volatile("s_nop 7\n\ts_nop 7\n\ts_nop 7" ::);  // MFMA->VALU hazard pad

  // ---- softmax over m (lane-local), write av[t][h] to LDS @32K ----
  {
    const int hh = l & 15;
    if (hh < 8) {
      const float sb = scoreb[hh];
      const float s0 = sacc[0] + sb, s1 = sacc[1] + sb;
      const float s2 = sacc[2] + sb, s3 = sacc[3] + sb;
      const float mx = fmaxf(fmaxf(s0, s1), fmaxf(s2, s3));
      const float e0 = __expf(s0 - mx), e1 = __expf(s1 - mx);
      const float e2 = __expf(s2 - mx), e3 = __expf(s3 - mx);
      const float inv = 1.f / (e0 + e1 + e2 + e3);
      f32x4 av; av[0] = e0 * inv; av[1] = e1 * inv; av[2] = e2 * inv; av[3] = e3 * inv;
      const int t = (w << 2) + (l >> 4);
      *(f32x4*)(smem + 32768 + (((t << 3) + hh) << 4)) = av;
    }
  }
  __syncthreads();

  // ---- blend: o_mid[t][f] = sum_m av*V + bv; scatter to frag LDS @0 ----
  {
    unsigned short* omid = (unsigned short*)(smem);
    #pragma unroll
    for (int c2 = 0; c2 < 2; ++c2) {
      const int ff = ((ct0 + c2) << 5) + (l & 31);
      const float bvf = in_b[1024 + ff];
      const int ktf = ff >> 4;
      const int laneL = ((l >> 3) & 1) << 5;
      const int elem = ff & 7;
      #pragma unroll
      for (int rt = 0; rt < 4; ++rt) {
        #pragma unroll
        for (int tt = 0; tt < 4; ++tt) {
          const int t = (rt << 3) + (tt << 1) + (l >> 5);
          const f32x4 av = *(const f32x4*)(smem + 32768 + (((t << 3) + w) << 4));
          const float o = av[0] * acc[rt][c2][tt * 4 + 0]
                        + av[1] * acc[rt][c2][tt * 4 + 1]
                        + av[2] * acc[rt][c2][tt * 4 + 2]
                        + av[3] * acc[rt][c2][tt * 4 + 3] + bvf;
          omid[((ktf << 6) + t + laneL) * 8 + elem] = f2bf(o);
        }
      }
    }
  }
  __syncthreads();

  // ---- out-projection GEMM: [32 x 512] x Wo^T ----
  f32x16 oa0, oa1;
  #pragma unroll
  for (int r = 0; r < 16; ++r) { oa0[r] = 0.f; oa1[r] = 0.f; }
  const int a_off = l << 4;
  #pragma unroll 4
  for (int kt = 0; kt < 32; ++kt) {
    const short8 a = *(const short8*)(smem + (kt << 10) + a_off);
    const short8 b0 = *(const short8*)(WoB + (((ct0 * 32 + kt) << 6) + l) * 8);
    const short8 b1 = *(const short8*)(WoB + ((((ct0 + 1) * 32 + kt) << 6) + l) * 8);
    mfma32(oa0, a, b0);
    mfma32(oa1, a, b1);
  }
  asm volatile("s_nop 7\n\ts_nop 7\n\ts_nop 7" ::);  // MFMA->VALU hazard pad

  // ---- LayerNorm: per-wave partial stats -> LDS @36K -> combine -> store ----
  {
    const int g0 = (ct0 << 5) + (l & 31);
    const int g1 = g0 + 32;
    const float ob0 = out_b[g0], ob1 = out_b[g1];
    const float gm0 = gamma[g0], gm1 = gamma[g1];
    const float bt0 = beta[g0],  bt1 = beta[g1];
    float* stats = (float*)(smem + 36864);  // [32][8 waves][2]
    #pragma unroll
    for (int r = 0; r < 16; ++r) {
      const float v0 = oa0[r] + ob0, v1 = oa1[r] + ob1;
      float s = v0 + v1, qq = v0 * v0 + v1 * v1;
      s += __shfl_xor(s, 16); qq += __shfl_xor(qq, 16);
      s += __shfl_xor(s, 8);  qq += __shfl_xor(qq, 8);
      s += __shfl_xor(s, 4);  qq += __shfl_xor(qq, 4);
      s += __shfl_xor(s, 2);  qq += __shfl_xor(qq, 2);
      s += __shfl_xor(s, 1);  qq += __shfl_xor(qq, 1);
      if ((l & 31) == 0) {
        const int t = (r & 3) + ((r >> 2) << 3) + ((l >> 5) << 2);
        stats[(t << 4) + (w << 1)] = s;
        stats[(t << 4) + (w << 1) + 1] = qq;
      }
    }
    __syncthreads();
    #pragma unroll
    for (int r = 0; r < 16; ++r) {
      const int t = (r & 3) + ((r >> 2) << 3) + ((l >> 5) << 2);
      const float* st = stats + (t << 4);
      float s = 0.f, qq = 0.f;
      #pragma unroll
      for (int ww = 0; ww < 8; ++ww) { s += st[2 * ww]; qq += st[2 * ww + 1]; }
      const float mu = s * 0.001953125f;
      const float rs = rsqrtf(qq * 0.001953125f - mu * mu + 1e-5f);
      const float v0 = oa0[r] + ob0, v1 = oa1[r] + ob1;
      float* op = out + (size_t)(tok0 + t) * 512;
      op[g0] = (v0 - mu) * rs * gm0 + bt0;
      op[g1] = (v1 - mu) * rs * gm1 + bt1;
    }
  }
}

extern "C" void kernel_launch(void* const* d_in, const int* in_sizes, int n_in,
                              void* d_out, int out_size, void* d_ws, size_t ws_size,
                              hipStream_t stream) {
  const float* f0      = (const float*)d_in[0];
  const float* f1      = (const float*)d_in[1];
  const float* f2      = (const float*)d_in[2];
  const float* f3      = (const float*)d_in[3];
  const float* q_param = (const float*)d_in[4];
  const float* in_w    = (const float*)d_in[5];
  const float* in_b    = (const float*)d_in[6];
  const float* out_w   = (const float*)d_in[7];
  const float* out_b   = (const float*)d_in[8];
  const float* gamma   = (const float*)d_in[9];
  const float* beta    = (const float*)d_in[10];
  float* out = (float*)d_out;

  char* ws = (char*)d_ws;
  float* scoreb          = (float*)ws;                      // 64 B
  unsigned short* wscB   = (unsigned short*)(ws + 4096);    // 16 KB
  unsigned short* WvB    = (unsigned short*)(ws + 20480);   // 512 KB
  unsigned short* WoB    = (unsigned short*)(ws + 544768);  // 512 KB

  tdcp_k0<<<136, 512, 0, stream>>>(q_param, in_w, in_b, out_w,
                                   scoreb, wscB, WvB, WoB);
  tdcp_k1<<<1024, 512, 0, stream>>>(f0, f1, f2, f3, in_b,
                                    scoreb, wscB, WvB, WoB,
                                    out_b, gamma, beta, out);
}